// Round 8
// baseline (485.021 us; speedup 1.0000x reference)
//
#include <hip/hip_runtime.h>
#include <math.h>

// Problem constants (from reference)
#define NB   512   // batch
#define DIMD 256   // dim
#define CBN  256   // codewords per codebook
#define NCBK 8     // codebooks
#define NITR 5     // refinement iterations
#define TOPK 16    // K_CUTOFF
#define W2   2048  // NCBK*CBN

// pair index for m<n among 8 codebooks (28 pairs)
__device__ __forceinline__ int pidx(int m, int n) {
    return m * 8 - (m * (m + 1)) / 2 + (n - m - 1);
}

__device__ const int PM28[28] = {0,0,0,0,0,0,0, 1,1,1,1,1,1, 2,2,2,2,2, 3,3,3,3, 4,4,4, 5,5, 6};
__device__ const int PN28[28] = {1,2,3,4,5,6,7, 2,3,4,5,6,7, 3,4,5,6,7, 4,5,6,7, 5,6,7, 6,7, 7};

__device__ __forceinline__ bool kgt(double v1, int k1, double v2, int k2) {
    return (v1 > v2) || (v1 == v2 && k1 > k2);
}

// Bitonic sort of 64 (v,k) pairs, one per lane, ascending by (v,k). No barriers.
__device__ __forceinline__ void wave_sort64(double& v, int& k, int lane) {
#pragma unroll
    for (int size = 2; size <= 64; size <<= 1) {
#pragma unroll
        for (int stride = size >> 1; stride > 0; stride >>= 1) {
            double pv = __shfl_xor(v, stride, 64);
            int pk = __shfl_xor(k, stride, 64);
            bool asc = ((lane & size) == 0);
            bool lower = (lane & stride) == 0;
            bool gt = kgt(v, k, pv, pk);
            bool take = asc ? (lower ? gt : !gt) : (lower ? !gt : gt);
            if (take) { v = pv; k = pk; }
        }
    }
}

// Stable top-16 of 256 (v,k) pairs (one per thread, 4 waves).
__device__ __forceinline__ void top16_256(double v, int k, int tid,
                                          double* cv, int* ck,
                                          double* outV, int* outK) {
    int lane = tid & 63, wave = tid >> 6;
    wave_sort64(v, k, lane);
    if (lane < 16) { cv[wave * 16 + lane] = v; ck[wave * 16 + lane] = k; }
    __syncthreads();
    if (wave == 0) {
        double mv = cv[lane]; int mk = ck[lane];
        wave_sort64(mv, mk, lane);
        if (lane < 16) { outV[lane] = mv; outK[lane] = mk; }
    }
    __syncthreads();
}

// Stable argmin of 256 (v,k): lexicographic min. Result in outK[0] (and outV[0]).
__device__ __forceinline__ void argmin_256(double v, int k, int tid,
                                           double* cv, int* ck,
                                           double* outV, int* outK) {
    int lane = tid & 63, wave = tid >> 6;
#pragma unroll
    for (int st = 32; st > 0; st >>= 1) {
        double pv = __shfl_xor(v, st, 64);
        int pk = __shfl_xor(k, st, 64);
        if (kgt(v, k, pv, pk)) { v = pv; k = pk; }
    }
    if (lane == 0) { cv[wave] = v; ck[wave] = k; }
    __syncthreads();
    if (tid == 0) {
        double bv = cv[0]; int bk = ck[0];
        for (int w = 1; w < 4; ++w)
            if (kgt(bv, bk, cv[w], ck[w])) { bv = cv[w]; bk = ck[w]; }
        outV[0] = bv; outK[0] = bk;
    }
    __syncthreads();
}

// ---- GEMM: Out[i][j] = sum_k A[i][k]*B[j][k]; fp32 in, fp64 accum, fp32 out ----
__global__ __launch_bounds__(256) void k_gemm_nt(
        const float* __restrict__ A, const float* __restrict__ B,
        float* __restrict__ Out, int ldo) {
    __shared__ float As[64][17];
    __shared__ float Bs[64][17];
    int tid = threadIdx.x;
    int ty = tid >> 4, tx = tid & 15;
    int row0 = blockIdx.y * 64, col0 = blockIdx.x * 64;
    int lr = tid >> 2, lk = (tid & 3) * 4;
    double acc[4][4] = {};
    for (int k0 = 0; k0 < DIMD; k0 += 16) {
        float4 av = *(const float4*)(A + (size_t)(row0 + lr) * DIMD + k0 + lk);
        float4 bv = *(const float4*)(B + (size_t)(col0 + lr) * DIMD + k0 + lk);
        __syncthreads();
        As[lr][lk + 0] = av.x; As[lr][lk + 1] = av.y;
        As[lr][lk + 2] = av.z; As[lr][lk + 3] = av.w;
        Bs[lr][lk + 0] = bv.x; Bs[lr][lk + 1] = bv.y;
        Bs[lr][lk + 2] = bv.z; Bs[lr][lk + 3] = bv.w;
        __syncthreads();
#pragma unroll 4
        for (int kk = 0; kk < 16; ++kk) {
            double a[4], b[4];
#pragma unroll
            for (int i = 0; i < 4; ++i) a[i] = (double)As[4 * ty + i][kk];
#pragma unroll
            for (int j = 0; j < 4; ++j) b[j] = (double)Bs[4 * tx + j][kk];
#pragma unroll
            for (int i = 0; i < 4; ++i)
#pragma unroll
                for (int j = 0; j < 4; ++j) acc[i][j] = fma(a[i], b[j], acc[i][j]);
        }
    }
#pragma unroll
    for (int i = 0; i < 4; ++i)
#pragma unroll
        for (int j = 0; j < 4; ++j)
            Out[(size_t)(row0 + 4 * ty + i) * ldo + col0 + 4 * tx + j] = (float)acc[i][j];
}

// ---- Symmetric Gram GEMM: G = C*C^T (upper blocks + mirror) + Gdiag on diag blocks ----
__global__ __launch_bounds__(256) void k_gemm_sym(
        const float* __restrict__ C, float* __restrict__ Out,
        float* __restrict__ Gdiag) {
    __shared__ float As[64][17];
    __shared__ float Bs[64][17];
    __shared__ float Tr[64][65];
    int tid = threadIdx.x;
    int ty = tid >> 4, tx = tid & 15;
    int t = blockIdx.x, bi = 0;
    while (t >= 32 - bi) { t -= 32 - bi; ++bi; }
    int bj = bi + t;
    int row0 = bi * 64, col0 = bj * 64;
    int lr = tid >> 2, lk = (tid & 3) * 4;
    double acc[4][4] = {};
    for (int k0 = 0; k0 < DIMD; k0 += 16) {
        float4 av = *(const float4*)(C + (size_t)(row0 + lr) * DIMD + k0 + lk);
        float4 bv = *(const float4*)(C + (size_t)(col0 + lr) * DIMD + k0 + lk);
        __syncthreads();
        As[lr][lk + 0] = av.x; As[lr][lk + 1] = av.y;
        As[lr][lk + 2] = av.z; As[lr][lk + 3] = av.w;
        Bs[lr][lk + 0] = bv.x; Bs[lr][lk + 1] = bv.y;
        Bs[lr][lk + 2] = bv.z; Bs[lr][lk + 3] = bv.w;
        __syncthreads();
#pragma unroll 4
        for (int kk = 0; kk < 16; ++kk) {
            double a[4], b[4];
#pragma unroll
            for (int i = 0; i < 4; ++i) a[i] = (double)As[4 * ty + i][kk];
#pragma unroll
            for (int j = 0; j < 4; ++j) b[j] = (double)Bs[4 * tx + j][kk];
#pragma unroll
            for (int i = 0; i < 4; ++i)
#pragma unroll
                for (int j = 0; j < 4; ++j) acc[i][j] = fma(a[i], b[j], acc[i][j]);
        }
    }
#pragma unroll
    for (int i = 0; i < 4; ++i)
#pragma unroll
        for (int j = 0; j < 4; ++j) {
            Out[(size_t)(row0 + 4 * ty + i) * W2 + col0 + 4 * tx + j] = (float)acc[i][j];
            if (bi == bj && (4 * ty + i) == (4 * tx + j))
                Gdiag[row0 + 4 * ty + i] = (float)acc[i][j];
        }
    if (bi != bj) {
        __syncthreads();
#pragma unroll
        for (int i = 0; i < 4; ++i)
#pragma unroll
            for (int j = 0; j < 4; ++j)
                Tr[4 * tx + j][4 * ty + i] = (float)acc[i][j];
        __syncthreads();
#pragma unroll
        for (int i = 0; i < 4; ++i)
#pragma unroll
            for (int j = 0; j < 4; ++j)
                Out[(size_t)(col0 + 4 * ty + i) * W2 + row0 + 4 * tx + j] = Tr[4 * ty + i][4 * tx + j];
    }
}

// ---- persistent fused kernel: init argmax + xnorm + all 5 refinement iterations ----
__global__ __launch_bounds__(256, 4) void k_iter5(
        const float* __restrict__ G, const float* __restrict__ Xc,
        const float* __restrict__ Gdiag, const float* __restrict__ Xw,
        const float* __restrict__ bias, const float* __restrict__ x,
        int* __restrict__ out) {
    int b = blockIdx.x, tid = threadIdx.x;
    __shared__ float Dsh[28 * 256];          // 28 KB
    __shared__ float Ecr[NCBK * NCBK * 16];  // 4 KB
    __shared__ int idxL[NCBK];
    __shared__ int jm[NCBK];
    __shared__ double gmat[64], Xcj[NCBK], Sj[NCBK], jdiag[NCBK];
    __shared__ double xes_sh, xnb_sh;
    __shared__ int changed_sh;
    __shared__ double tv[NCBK][16];
    __shared__ int tk[NCBK][16];
    __shared__ int amr[NCBK][16];
    __shared__ double l1v[4][16]; __shared__ int l1k[4][16];
    __shared__ double l2v[2][16]; __shared__ int l2k[2][16];
    __shared__ double cv[64]; __shared__ int ck[64];
    __shared__ double tmpV[16]; __shared__ int tmpK[16];

    int lane = tid & 63, wave = tid >> 6;

    // ---- prologue: xnorm (uniform-shift invariant), iteration-invariant regs ----
    {
        float xv = x[(size_t)b * DIMD + tid];
        double s = (double)xv * xv;
#pragma unroll
        for (int st = 32; st > 0; st >>= 1) s += __shfl_down(s, st, 64);
        if (lane == 0) cv[wave] = s;
    }
    __syncthreads();
    if (tid == 0) xnb_sh = cv[0] + cv[1] + cv[2] + cv[3];
    __syncthreads();
    double xnb = xnb_sh;

    float xcr[NCBK], gdr[NCBK];  // Xc[b][n*256+tid], Gdiag[n*256+tid]
#pragma unroll
    for (int n = 0; n < NCBK; ++n) {
        xcr[n] = Xc[(size_t)b * W2 + n * CBN + tid];
        gdr[n] = Gdiag[n * CBN + tid];
    }

    // ---- initial argmax: first max of (Xw+bias) == argmin of (-val, idx) ----
#pragma unroll
    for (int n = 0; n < NCBK; ++n) {
        double v = -((double)Xw[(size_t)b * W2 + n * CBN + tid] + (double)bias[n * CBN + tid]);
        argmin_256(v, tid, tid, cv, ck, tmpV, tmpK);
        if (tid == 0) idxL[n] = tmpK[0];
    }
    __syncthreads();

    for (int it = 0; it < NITR; ++it) {
        if (tid < NCBK) jm[tid] = tid * CBN + idxL[tid];
        __syncthreads();

        // ---- bulk prefetch: all 64 cost-phase G values into registers ----
        size_t rbase[NCBK];
#pragma unroll
        for (int m = 0; m < NCBK; ++m) rbase[m] = (size_t)jm[m] * W2;
        float gv[NCBK][NCBK];  // gv[n][m] = G[jm[m]][n*256+tid]
#pragma unroll
        for (int n = 0; n < NCBK; ++n)
#pragma unroll
            for (int m = 0; m < NCBK; ++m)
                gv[n][m] = G[rbase[m] + n * CBN + tid];

        if (tid < 64) gmat[tid] = (double)G[rbase[tid >> 3] + jm[tid & 7]];
        if (tid >= 64 && tid < 72) Xcj[tid - 64] = (double)Xc[(size_t)b * W2 + jm[tid - 64]];
        if (tid >= 72 && tid < 80) jdiag[tid - 72] = (double)Gdiag[jm[tid - 72]];
        __syncthreads();
        if (tid < NCBK) {
            double s = 0.0;
            for (int mp = 0; mp < NCBK; ++mp) s += gmat[mp * 8 + tid];
            Sj[tid] = s - Xcj[tid];
        }
        __syncthreads();
        if (tid == 0) {
            double e = xnb;
            for (int m = 0; m < NCBK; ++m) e += Sj[m] - Xcj[m];
            xes_sh = e;
        }
        __syncthreads();

        // ---- cost phase: 8 sorts back-to-back, data all in registers ----
#pragma unroll
        for (int n = 0; n < NCBK; ++n) {
            double s = -(double)xcr[n];
            double gjn = 0.0;
#pragma unroll
            for (int m = 0; m < NCBK; ++m) {
                double g = (double)gv[n][m];
                s += g;
                if (m == n) gjn = g;
            }
            double cost = (xes_sh - 2.0 * Sj[n] + jdiag[n]) + 2.0 * (s - gjn) + (double)gdr[n];
            top16_256(cost, tid, tid, cv, ck, tv[n], tk[n]);
        }
        if (tid < 128) { int m = tid >> 4, i = tid & 15; amr[m][i] = m * CBN + tk[m][i]; }
        __syncthreads();

        // ---- Ecr via G symmetry (rows jm are L2-warm from cost loads) ----
        for (int t = tid; t < NCBK * NCBK * 16; t += 256) {
            int m = t >> 7, nn = (t >> 4) & 7, ii = t & 15;
            Ecr[t] = G[(size_t)jm[nn] * W2 + amr[m][ii]];
        }
        __syncthreads();

        // ---- D-tiles: prefetch 28 scattered values, then combine ----
        {
            int i = tid >> 4, j = tid & 15;
            int ar[NCBK], ac[NCBK];
#pragma unroll
            for (int m = 0; m < NCBK; ++m) { ar[m] = amr[m][i]; ac[m] = amr[m][j]; }
            float dreg[28];
#pragma unroll
            for (int p = 0; p < 28; ++p)
                dreg[p] = G[(size_t)ar[PM28[p]] * W2 + ac[PN28[p]]];
#pragma unroll
            for (int p = 0; p < 28; ++p) {
                int m = PM28[p], n = PN28[p];
                double v = (double)dreg[p]
                         - (double)Ecr[m * 128 + n * 16 + i]
                         - (double)Ecr[n * 128 + m * 16 + j]
                         + gmat[m * 8 + n];
                Dsh[p * 256 + tid] = (float)v;
            }
        }
        __syncthreads();
        double xes = xes_sh;

        // ---- tournament ----
        for (int g = 0; g < 4; ++g) {
            int i = tid >> 4, j = tid & 15;
            double val = tv[2 * g][i] + tv[2 * g + 1][j] - xes
                       + 2.0 * (double)Dsh[pidx(2 * g, 2 * g + 1) * 256 + tid];
            top16_256(val, tid, tid, cv, ck, l1v[g], l1k[g]);
        }
        for (int G2 = 0; G2 < 2; ++G2) {
            int a = tid >> 4, b2 = tid & 15;
            int pe = l1k[2 * G2][a], po = l1k[2 * G2 + 1][b2];
            int ie = pe >> 4, io = pe & 15, je = po >> 4, jo = po & 15;
            int c0 = 4 * G2, c1 = 4 * G2 + 1, c2 = 4 * G2 + 2, c3 = 4 * G2 + 3;
            double cross = (double)Dsh[pidx(c0, c2) * 256 + ie * 16 + je]
                         + (double)Dsh[pidx(c0, c3) * 256 + ie * 16 + jo]
                         + (double)Dsh[pidx(c1, c2) * 256 + io * 16 + je]
                         + (double)Dsh[pidx(c1, c3) * 256 + io * 16 + jo];
            double val = l1v[2 * G2][a] + l1v[2 * G2 + 1][b2] - xes + 2.0 * cross;
            top16_256(val, tid, tid, cv, ck, tmpV, tmpK);
            if (tid < 16) {
                l2v[G2][tid] = tmpV[tid];
                int kk = tmpK[tid];
                l2k[G2][tid] = (l1k[2 * G2][kk >> 4] << 8) | l1k[2 * G2 + 1][kk & 15];
            }
            __syncthreads();
        }
        {
            int a = tid >> 4, b2 = tid & 15;
            int p0 = l2k[0][a], p1 = l2k[1][b2];
            int se[4] = { (p0 >> 12) & 15, (p0 >> 8) & 15, (p0 >> 4) & 15, p0 & 15 };
            int so[4] = { (p1 >> 12) & 15, (p1 >> 8) & 15, (p1 >> 4) & 15, p1 & 15 };
            double cross = 0.0;
#pragma unroll
            for (int mm = 0; mm < 4; ++mm)
#pragma unroll
                for (int q = 0; q < 4; ++q)
                    cross += (double)Dsh[pidx(mm, 4 + q) * 256 + se[mm] * 16 + so[q]];
            double val = l2v[0][a] + l2v[1][b2] - xes + 2.0 * cross;
            argmin_256(val, tid, tid, cv, ck, tmpV, tmpK);
            if (tid == 0) {
                int k = tmpK[0];
                int a0 = k >> 4, b0 = k & 15;
                int p0w = l2k[0][a0], p1w = l2k[1][b0];
                int sl[8] = { (p0w >> 12) & 15, (p0w >> 8) & 15, (p0w >> 4) & 15, p0w & 15,
                              (p1w >> 12) & 15, (p1w >> 8) & 15, (p1w >> 4) & 15, p1w & 15 };
                int changed = 0;
                for (int n = 0; n < NCBK; ++n) {
                    int ci = tk[n][sl[n]];
                    if (ci != idxL[n]) changed = 1;
                    idxL[n] = ci;
                }
                changed_sh = changed;
            }
        }
        __syncthreads();
        if (!changed_sh) break;
    }
    if (tid < NCBK) out[b * NCBK + tid] = idxL[tid];
}

extern "C" void kernel_launch(void* const* d_in, const int* in_sizes, int n_in,
                              void* d_out, int out_size, void* d_ws, size_t ws_size,
                              hipStream_t stream) {
    const float* x    = (const float*)d_in[0];  // (512, 256)
    const float* w    = (const float*)d_in[1];  // (2048, 256)
    const float* bias = (const float*)d_in[2];  // (2048,)
    const float* c    = (const float*)d_in[3];  // (2048, 256)
    int* out = (int*)d_out;                     // (512, 8) int32
    char* ws = (char*)d_ws;

    // workspace layout (~25.2 MB, fp32 tables)
    float*  G     = (float*) (ws);               // 2048*2048*4 = 16,777,216
    float*  Xc    = (float*) (ws + 16777216);    // 512*2048*4 = 4,194,304
    float*  Xw    = (float*) (ws + 20971520);    // 512*2048*4 = 4,194,304
    float*  Gdiag = (float*) (ws + 25165824);    // 2048*4     = 8,192

    k_gemm_nt<<<dim3(32, 8), 256, 0, stream>>>(x, w, Xw, W2);
    k_gemm_nt<<<dim3(32, 8), 256, 0, stream>>>(x, c, Xc, W2);
    k_gemm_sym<<<528, 256, 0, stream>>>(c, G, Gdiag);
    k_iter5<<<NB, 256, 0, stream>>>(G, Xc, Gdiag, Xw, bias, x, out);
}

// Round 9
// 413.878 us; speedup vs baseline: 1.1719x; 1.1719x over previous
//
#include <hip/hip_runtime.h>
#include <math.h>

// Problem constants (from reference)
#define NB   512   // batch
#define DIMD 256   // dim
#define CBN  256   // codewords per codebook
#define NCBK 8     // codebooks
#define NITR 5     // refinement iterations
#define TOPK 16    // K_CUTOFF
#define W2   2048  // NCBK*CBN

// pair index for m<n among 8 codebooks (28 pairs)
__device__ __forceinline__ int pidx(int m, int n) {
    return m * 8 - (m * (m + 1)) / 2 + (n - m - 1);
}

__device__ const int PM28[28] = {0,0,0,0,0,0,0, 1,1,1,1,1,1, 2,2,2,2,2, 3,3,3,3, 4,4,4, 5,5, 6};
__device__ const int PN28[28] = {1,2,3,4,5,6,7, 2,3,4,5,6,7, 3,4,5,6,7, 4,5,6,7, 5,6,7, 6,7, 7};

__device__ __forceinline__ bool kgt(double v1, int k1, double v2, int k2) {
    return (v1 > v2) || (v1 == v2 && k1 > k2);
}

// Bitonic sort of 64 (v,k) pairs, one per lane, ascending by (v,k). No barriers.
__device__ __forceinline__ void wave_sort64(double& v, int& k, int lane) {
#pragma unroll
    for (int size = 2; size <= 64; size <<= 1) {
#pragma unroll
        for (int stride = size >> 1; stride > 0; stride >>= 1) {
            double pv = __shfl_xor(v, stride, 64);
            int pk = __shfl_xor(k, stride, 64);
            bool asc = ((lane & size) == 0);
            bool lower = (lane & stride) == 0;
            bool gt = kgt(v, k, pv, pk);
            bool take = asc ? (lower ? gt : !gt) : (lower ? !gt : gt);
            if (take) { v = pv; k = pk; }
        }
    }
}

// Stable top-16 of 256 (v,k) pairs (one per thread, 4 waves).
__device__ __forceinline__ void top16_256(double v, int k, int tid,
                                          double* cv, int* ck,
                                          double* outV, int* outK) {
    int lane = tid & 63, wave = tid >> 6;
    wave_sort64(v, k, lane);
    if (lane < 16) { cv[wave * 16 + lane] = v; ck[wave * 16 + lane] = k; }
    __syncthreads();
    if (wave == 0) {
        double mv = cv[lane]; int mk = ck[lane];
        wave_sort64(mv, mk, lane);
        if (lane < 16) { outV[lane] = mv; outK[lane] = mk; }
    }
    __syncthreads();
}

// Stable argmin of 256 (v,k): lexicographic min. Result in outK[0] (and outV[0]).
__device__ __forceinline__ void argmin_256(double v, int k, int tid,
                                           double* cv, int* ck,
                                           double* outV, int* outK) {
    int lane = tid & 63, wave = tid >> 6;
#pragma unroll
    for (int st = 32; st > 0; st >>= 1) {
        double pv = __shfl_xor(v, st, 64);
        int pk = __shfl_xor(k, st, 64);
        if (kgt(v, k, pv, pk)) { v = pv; k = pk; }
    }
    if (lane == 0) { cv[wave] = v; ck[wave] = k; }
    __syncthreads();
    if (tid == 0) {
        double bv = cv[0]; int bk = ck[0];
        for (int w = 1; w < 4; ++w)
            if (kgt(bv, bk, cv[w], ck[w])) { bv = cv[w]; bk = ck[w]; }
        outV[0] = bv; outK[0] = bk;
    }
    __syncthreads();
}

// ---- GEMM: Out[i][j] = sum_k A[i][k]*B[j][k]; fp32 in, fp64 accum, fp32 out ----
__global__ __launch_bounds__(256) void k_gemm_nt(
        const float* __restrict__ A, const float* __restrict__ B,
        float* __restrict__ Out, int ldo) {
    __shared__ float As[64][17];
    __shared__ float Bs[64][17];
    int tid = threadIdx.x;
    int ty = tid >> 4, tx = tid & 15;
    int row0 = blockIdx.y * 64, col0 = blockIdx.x * 64;
    int lr = tid >> 2, lk = (tid & 3) * 4;
    double acc[4][4] = {};
    for (int k0 = 0; k0 < DIMD; k0 += 16) {
        float4 av = *(const float4*)(A + (size_t)(row0 + lr) * DIMD + k0 + lk);
        float4 bv = *(const float4*)(B + (size_t)(col0 + lr) * DIMD + k0 + lk);
        __syncthreads();
        As[lr][lk + 0] = av.x; As[lr][lk + 1] = av.y;
        As[lr][lk + 2] = av.z; As[lr][lk + 3] = av.w;
        Bs[lr][lk + 0] = bv.x; Bs[lr][lk + 1] = bv.y;
        Bs[lr][lk + 2] = bv.z; Bs[lr][lk + 3] = bv.w;
        __syncthreads();
#pragma unroll 4
        for (int kk = 0; kk < 16; ++kk) {
            double a[4], b[4];
#pragma unroll
            for (int i = 0; i < 4; ++i) a[i] = (double)As[4 * ty + i][kk];
#pragma unroll
            for (int j = 0; j < 4; ++j) b[j] = (double)Bs[4 * tx + j][kk];
#pragma unroll
            for (int i = 0; i < 4; ++i)
#pragma unroll
                for (int j = 0; j < 4; ++j) acc[i][j] = fma(a[i], b[j], acc[i][j]);
        }
    }
#pragma unroll
    for (int i = 0; i < 4; ++i)
#pragma unroll
        for (int j = 0; j < 4; ++j)
            Out[(size_t)(row0 + 4 * ty + i) * ldo + col0 + 4 * tx + j] = (float)acc[i][j];
}

// ---- Symmetric Gram GEMM: G = C*C^T (upper blocks + mirror) + Gdiag on diag blocks ----
__global__ __launch_bounds__(256) void k_gemm_sym(
        const float* __restrict__ C, float* __restrict__ Out,
        float* __restrict__ Gdiag) {
    __shared__ float As[64][17];
    __shared__ float Bs[64][17];
    __shared__ float Tr[64][65];
    int tid = threadIdx.x;
    int ty = tid >> 4, tx = tid & 15;
    int t = blockIdx.x, bi = 0;
    while (t >= 32 - bi) { t -= 32 - bi; ++bi; }
    int bj = bi + t;
    int row0 = bi * 64, col0 = bj * 64;
    int lr = tid >> 2, lk = (tid & 3) * 4;
    double acc[4][4] = {};
    for (int k0 = 0; k0 < DIMD; k0 += 16) {
        float4 av = *(const float4*)(C + (size_t)(row0 + lr) * DIMD + k0 + lk);
        float4 bv = *(const float4*)(C + (size_t)(col0 + lr) * DIMD + k0 + lk);
        __syncthreads();
        As[lr][lk + 0] = av.x; As[lr][lk + 1] = av.y;
        As[lr][lk + 2] = av.z; As[lr][lk + 3] = av.w;
        Bs[lr][lk + 0] = bv.x; Bs[lr][lk + 1] = bv.y;
        Bs[lr][lk + 2] = bv.z; Bs[lr][lk + 3] = bv.w;
        __syncthreads();
#pragma unroll 4
        for (int kk = 0; kk < 16; ++kk) {
            double a[4], b[4];
#pragma unroll
            for (int i = 0; i < 4; ++i) a[i] = (double)As[4 * ty + i][kk];
#pragma unroll
            for (int j = 0; j < 4; ++j) b[j] = (double)Bs[4 * tx + j][kk];
#pragma unroll
            for (int i = 0; i < 4; ++i)
#pragma unroll
                for (int j = 0; j < 4; ++j) acc[i][j] = fma(a[i], b[j], acc[i][j]);
        }
    }
#pragma unroll
    for (int i = 0; i < 4; ++i)
#pragma unroll
        for (int j = 0; j < 4; ++j) {
            Out[(size_t)(row0 + 4 * ty + i) * W2 + col0 + 4 * tx + j] = (float)acc[i][j];
            if (bi == bj && (4 * ty + i) == (4 * tx + j))
                Gdiag[row0 + 4 * ty + i] = (float)acc[i][j];
        }
    if (bi != bj) {
        __syncthreads();
#pragma unroll
        for (int i = 0; i < 4; ++i)
#pragma unroll
            for (int j = 0; j < 4; ++j)
                Tr[4 * tx + j][4 * ty + i] = (float)acc[i][j];
        __syncthreads();
#pragma unroll
        for (int i = 0; i < 4; ++i)
#pragma unroll
            for (int j = 0; j < 4; ++j)
                Out[(size_t)(col0 + 4 * ty + i) * W2 + row0 + 4 * tx + j] = Tr[4 * ty + i][4 * tx + j];
    }
}

// ---- persistent fused kernel: init argmax + xnorm + all 5 refinement iterations ----
__global__ __launch_bounds__(256) void k_iter5(
        const float* __restrict__ G, const float* __restrict__ Xc,
        const float* __restrict__ Gdiag, const float* __restrict__ Xw,
        const float* __restrict__ bias, const float* __restrict__ x,
        int* __restrict__ out) {
    int b = blockIdx.x, tid = threadIdx.x;
    __shared__ float Dsh[28 * 256];          // 28 KB
    __shared__ float Ecr[NCBK * NCBK * 16];  // 4 KB
    __shared__ int idxL[NCBK];
    __shared__ int jm[NCBK];
    __shared__ double gmat[64], Xcj[NCBK], Sj[NCBK], jdiag[NCBK];
    __shared__ double xes_sh, xnb_sh;
    __shared__ int changed_sh;
    __shared__ double tv[NCBK][16];
    __shared__ int tk[NCBK][16];
    __shared__ int amr[NCBK][16];
    __shared__ double l1v[4][16]; __shared__ int l1k[4][16];
    __shared__ double l2v[2][16]; __shared__ int l2k[2][16];
    __shared__ double cv[64]; __shared__ int ck[64];
    __shared__ double tmpV[16]; __shared__ int tmpK[16];

    int lane = tid & 63, wave = tid >> 6;

    // ---- prologue: xnorm (uniform-shift invariant) ----
    {
        float xv = x[(size_t)b * DIMD + tid];
        double s = (double)xv * xv;
#pragma unroll
        for (int st = 32; st > 0; st >>= 1) s += __shfl_down(s, st, 64);
        if (lane == 0) cv[wave] = s;
    }
    __syncthreads();
    if (tid == 0) xnb_sh = cv[0] + cv[1] + cv[2] + cv[3];
    __syncthreads();
    double xnb = xnb_sh;

    float xcr[NCBK], gdr[NCBK];  // Xc[b][n*256+tid], Gdiag[n*256+tid] (iteration-invariant)
#pragma unroll
    for (int n = 0; n < NCBK; ++n) {
        xcr[n] = Xc[(size_t)b * W2 + n * CBN + tid];
        gdr[n] = Gdiag[n * CBN + tid];
    }

    // ---- initial argmax: first max of (Xw+bias) == argmin of (-val, idx) ----
#pragma unroll
    for (int n = 0; n < NCBK; ++n) {
        double v = -((double)Xw[(size_t)b * W2 + n * CBN + tid] + (double)bias[n * CBN + tid]);
        argmin_256(v, tid, tid, cv, ck, tmpV, tmpK);
        if (tid == 0) idxL[n] = tmpK[0];
    }
    __syncthreads();

    for (int it = 0; it < NITR; ++it) {
        if (tid < NCBK) jm[tid] = tid * CBN + idxL[tid];
        __syncthreads();

        // jm rows base addresses (SGPR-friendly via LDS reads, constant-indexed)
        if (tid < 64) gmat[tid] = (double)G[(size_t)jm[tid >> 3] * W2 + jm[tid & 7]];
        if (tid >= 64 && tid < 72) Xcj[tid - 64] = (double)Xc[(size_t)b * W2 + jm[tid - 64]];
        if (tid >= 72 && tid < 80) jdiag[tid - 72] = (double)Gdiag[jm[tid - 72]];
        __syncthreads();
        if (tid < NCBK) {
            double s = 0.0;
            for (int mp = 0; mp < NCBK; ++mp) s += gmat[mp * 8 + tid];
            Sj[tid] = s - Xcj[tid];
        }
        __syncthreads();
        if (tid == 0) {
            double e = xnb;
            for (int m = 0; m < NCBK; ++m) e += Sj[m] - Xcj[m];
            xes_sh = e;
        }
        __syncthreads();

        // ---- cost phase: software-pipelined G prefetch (cur/nxt, 16 live floats) ----
        {
            int jr[NCBK];
#pragma unroll
            for (int m = 0; m < NCBK; ++m) jr[m] = jm[m];
            float cur[NCBK], nxt[NCBK];
#pragma unroll
            for (int m = 0; m < NCBK; ++m) cur[m] = G[(size_t)jr[m] * W2 + tid];
#pragma unroll
            for (int n = 0; n < NCBK; ++n) {
                if (n < NCBK - 1) {
#pragma unroll
                    for (int m = 0; m < NCBK; ++m)
                        nxt[m] = G[(size_t)jr[m] * W2 + (n + 1) * CBN + tid];
                }
                double s = -(double)xcr[n];
                double gjn = 0.0;
#pragma unroll
                for (int m = 0; m < NCBK; ++m) {
                    double g = (double)cur[m];
                    s += g;
                    if (m == n) gjn = g;
                }
                double cost = (xes_sh - 2.0 * Sj[n] + jdiag[n]) + 2.0 * (s - gjn) + (double)gdr[n];
                top16_256(cost, tid, tid, cv, ck, tv[n], tk[n]);
                if (n < NCBK - 1) {
#pragma unroll
                    for (int m = 0; m < NCBK; ++m) cur[m] = nxt[m];
                }
            }
        }
        if (tid < 128) { int m = tid >> 4, i = tid & 15; amr[m][i] = m * CBN + tk[m][i]; }
        __syncthreads();

        // ---- Ecr via G symmetry (rows jm are L2-warm from cost loads) ----
        for (int t = tid; t < NCBK * NCBK * 16; t += 256) {
            int m = t >> 7, nn = (t >> 4) & 7, ii = t & 15;
            Ecr[t] = G[(size_t)jm[nn] * W2 + amr[m][ii]];
        }
        __syncthreads();

        // ---- D-tiles: prefetch 28 scattered values, then combine ----
        {
            int i = tid >> 4, j = tid & 15;
            int ar[NCBK], ac[NCBK];
#pragma unroll
            for (int m = 0; m < NCBK; ++m) { ar[m] = amr[m][i]; ac[m] = amr[m][j]; }
            float dreg[28];
#pragma unroll
            for (int p = 0; p < 28; ++p)
                dreg[p] = G[(size_t)ar[PM28[p]] * W2 + ac[PN28[p]]];
#pragma unroll
            for (int p = 0; p < 28; ++p) {
                int m = PM28[p], n = PN28[p];
                double v = (double)dreg[p]
                         - (double)Ecr[m * 128 + n * 16 + i]
                         - (double)Ecr[n * 128 + m * 16 + j]
                         + gmat[m * 8 + n];
                Dsh[p * 256 + tid] = (float)v;
            }
        }
        __syncthreads();
        double xes = xes_sh;

        // ---- tournament ----
        for (int g = 0; g < 4; ++g) {
            int i = tid >> 4, j = tid & 15;
            double val = tv[2 * g][i] + tv[2 * g + 1][j] - xes
                       + 2.0 * (double)Dsh[pidx(2 * g, 2 * g + 1) * 256 + tid];
            top16_256(val, tid, tid, cv, ck, l1v[g], l1k[g]);
        }
        for (int G2 = 0; G2 < 2; ++G2) {
            int a = tid >> 4, b2 = tid & 15;
            int pe = l1k[2 * G2][a], po = l1k[2 * G2 + 1][b2];
            int ie = pe >> 4, io = pe & 15, je = po >> 4, jo = po & 15;
            int c0 = 4 * G2, c1 = 4 * G2 + 1, c2 = 4 * G2 + 2, c3 = 4 * G2 + 3;
            double cross = (double)Dsh[pidx(c0, c2) * 256 + ie * 16 + je]
                         + (double)Dsh[pidx(c0, c3) * 256 + ie * 16 + jo]
                         + (double)Dsh[pidx(c1, c2) * 256 + io * 16 + je]
                         + (double)Dsh[pidx(c1, c3) * 256 + io * 16 + jo];
            double val = l1v[2 * G2][a] + l1v[2 * G2 + 1][b2] - xes + 2.0 * cross;
            top16_256(val, tid, tid, cv, ck, tmpV, tmpK);
            if (tid < 16) {
                l2v[G2][tid] = tmpV[tid];
                int kk = tmpK[tid];
                l2k[G2][tid] = (l1k[2 * G2][kk >> 4] << 8) | l1k[2 * G2 + 1][kk & 15];
            }
            __syncthreads();
        }
        {
            int a = tid >> 4, b2 = tid & 15;
            int p0 = l2k[0][a], p1 = l2k[1][b2];
            int se[4] = { (p0 >> 12) & 15, (p0 >> 8) & 15, (p0 >> 4) & 15, p0 & 15 };
            int so[4] = { (p1 >> 12) & 15, (p1 >> 8) & 15, (p1 >> 4) & 15, p1 & 15 };
            double cross = 0.0;
#pragma unroll
            for (int mm = 0; mm < 4; ++mm)
#pragma unroll
                for (int q = 0; q < 4; ++q)
                    cross += (double)Dsh[pidx(mm, 4 + q) * 256 + se[mm] * 16 + so[q]];
            double val = l2v[0][a] + l2v[1][b2] - xes + 2.0 * cross;
            argmin_256(val, tid, tid, cv, ck, tmpV, tmpK);
            if (tid == 0) {
                int k = tmpK[0];
                int a0 = k >> 4, b0 = k & 15;
                int p0w = l2k[0][a0], p1w = l2k[1][b0];
                int sl[8] = { (p0w >> 12) & 15, (p0w >> 8) & 15, (p0w >> 4) & 15, p0w & 15,
                              (p1w >> 12) & 15, (p1w >> 8) & 15, (p1w >> 4) & 15, p1w & 15 };
                int changed = 0;
                for (int n = 0; n < NCBK; ++n) {
                    int ci = tk[n][sl[n]];
                    if (ci != idxL[n]) changed = 1;
                    idxL[n] = ci;
                }
                changed_sh = changed;
            }
        }
        __syncthreads();
        if (!changed_sh) break;
    }
    if (tid < NCBK) out[b * NCBK + tid] = idxL[tid];
}

extern "C" void kernel_launch(void* const* d_in, const int* in_sizes, int n_in,
                              void* d_out, int out_size, void* d_ws, size_t ws_size,
                              hipStream_t stream) {
    const float* x    = (const float*)d_in[0];  // (512, 256)
    const float* w    = (const float*)d_in[1];  // (2048, 256)
    const float* bias = (const float*)d_in[2];  // (2048,)
    const float* c    = (const float*)d_in[3];  // (2048, 256)
    int* out = (int*)d_out;                     // (512, 8) int32
    char* ws = (char*)d_ws;

    // workspace layout (~25.2 MB, fp32 tables)
    float*  G     = (float*) (ws);               // 2048*2048*4 = 16,777,216
    float*  Xc    = (float*) (ws + 16777216);    // 512*2048*4 = 4,194,304
    float*  Xw    = (float*) (ws + 20971520);    // 512*2048*4 = 4,194,304
    float*  Gdiag = (float*) (ws + 25165824);    // 2048*4     = 8,192

    k_gemm_nt<<<dim3(32, 8), 256, 0, stream>>>(x, w, Xw, W2);
    k_gemm_nt<<<dim3(32, 8), 256, 0, stream>>>(x, c, Xc, W2);
    k_gemm_sym<<<528, 256, 0, stream>>>(c, G, Gdiag);
    k_iter5<<<NB, 256, 0, stream>>>(G, Xc, Gdiag, Xw, bias, x, out);
}

// Round 11
// 380.084 us; speedup vs baseline: 1.2761x; 1.0889x over previous
//
#include <hip/hip_runtime.h>
#include <math.h>

// Problem constants (from reference)
#define NB   512   // batch
#define DIMD 256   // dim
#define CBN  256   // codewords per codebook
#define NCBK 8     // codebooks
#define NITR 5     // refinement iterations
#define TOPK 16    // K_CUTOFF
#define W2   2048  // NCBK*CBN

// pair index for m<n among 8 codebooks (28 pairs)
__device__ __forceinline__ int pidx(int m, int n) {
    return m * 8 - (m * (m + 1)) / 2 + (n - m - 1);
}

__device__ const int PM28[28] = {0,0,0,0,0,0,0, 1,1,1,1,1,1, 2,2,2,2,2, 3,3,3,3, 4,4,4, 5,5, 6};
__device__ const int PN28[28] = {1,2,3,4,5,6,7, 2,3,4,5,6,7, 3,4,5,6,7, 4,5,6,7, 5,6,7, 6,7, 7};

__device__ __forceinline__ bool kgt(double v1, int k1, double v2, int k2) {
    return (v1 > v2) || (v1 == v2 && k1 > k2);
}

// Bitonic sort of 64 (v,k) pairs, one per lane, ascending by (v,k). No barriers.
__device__ __forceinline__ void wave_sort64(double& v, int& k, int lane) {
#pragma unroll
    for (int size = 2; size <= 64; size <<= 1) {
#pragma unroll
        for (int stride = size >> 1; stride > 0; stride >>= 1) {
            double pv = __shfl_xor(v, stride, 64);
            int pk = __shfl_xor(k, stride, 64);
            bool asc = ((lane & size) == 0);
            bool lower = (lane & stride) == 0;
            bool gt = kgt(v, k, pv, pk);
            bool take = asc ? (lower ? gt : !gt) : (lower ? !gt : gt);
            if (take) { v = pv; k = pk; }
        }
    }
}

// Team-local stable top-16 of 256 (v,k) pairs (one 256-thread team = 4 waves).
// Both teams of a 512-thread block MUST call this in lockstep (global barriers).
__device__ __forceinline__ void top16_256t(double v, int k, int ttid,
                                           double* cvT, int* ckT,
                                           double* outV, int* outK) {
    int lane = ttid & 63, tw = ttid >> 6;
    wave_sort64(v, k, lane);
    if (lane < 16) { cvT[tw * 16 + lane] = v; ckT[tw * 16 + lane] = k; }
    __syncthreads();
    if (tw == 0) {
        double mv = cvT[lane]; int mk = ckT[lane];
        wave_sort64(mv, mk, lane);
        if (lane < 16) { outV[lane] = mv; outK[lane] = mk; }
    }
    __syncthreads();
}

// Team-local stable argmin of 256 (v,k). Lockstep across both teams.
__device__ __forceinline__ void argmin_256t(double v, int k, int ttid,
                                            double* cvT, int* ckT,
                                            double* outV, int* outK) {
    int lane = ttid & 63, tw = ttid >> 6;
#pragma unroll
    for (int st = 32; st > 0; st >>= 1) {
        double pv = __shfl_xor(v, st, 64);
        int pk = __shfl_xor(k, st, 64);
        if (kgt(v, k, pv, pk)) { v = pv; k = pk; }
    }
    if (lane == 0) { cvT[tw] = v; ckT[tw] = k; }
    __syncthreads();
    if (ttid == 0) {
        double bv = cvT[0]; int bk = ckT[0];
        for (int w = 1; w < 4; ++w)
            if (kgt(bv, bk, cvT[w], ckT[w])) { bv = cvT[w]; bk = ckT[w]; }
        outV[0] = bv; outK[0] = bk;
    }
    __syncthreads();
}

// Block-wide (512 threads) stable argmin; duplicate (v,k) entries are harmless.
__device__ __forceinline__ void argmin_512(double v, int k, int tid,
                                           double* cvA, int* ckA,
                                           double* outV, int* outK) {
    int lane = tid & 63, w8 = tid >> 6;
#pragma unroll
    for (int st = 32; st > 0; st >>= 1) {
        double pv = __shfl_xor(v, st, 64);
        int pk = __shfl_xor(k, st, 64);
        if (kgt(v, k, pv, pk)) { v = pv; k = pk; }
    }
    if (lane == 0) { cvA[w8] = v; ckA[w8] = k; }
    __syncthreads();
    if (tid == 0) {
        double bv = cvA[0]; int bk = ckA[0];
        for (int w = 1; w < 8; ++w)
            if (kgt(bv, bk, cvA[w], ckA[w])) { bv = cvA[w]; bk = ckA[w]; }
        outV[0] = bv; outK[0] = bk;
    }
    __syncthreads();
}

// ---- GEMM: Out[i][j] = sum_k A[i][k]*B[j][k]; fp32 in, fp64 accum, fp32 out ----
__global__ __launch_bounds__(256) void k_gemm_nt(
        const float* __restrict__ A, const float* __restrict__ B,
        float* __restrict__ Out, int ldo) {
    __shared__ float As[64][17];
    __shared__ float Bs[64][17];
    int tid = threadIdx.x;
    int ty = tid >> 4, tx = tid & 15;
    int row0 = blockIdx.y * 64, col0 = blockIdx.x * 64;
    int lr = tid >> 2, lk = (tid & 3) * 4;
    double acc[4][4] = {};
    for (int k0 = 0; k0 < DIMD; k0 += 16) {
        float4 av = *(const float4*)(A + (size_t)(row0 + lr) * DIMD + k0 + lk);
        float4 bv = *(const float4*)(B + (size_t)(col0 + lr) * DIMD + k0 + lk);
        __syncthreads();
        As[lr][lk + 0] = av.x; As[lr][lk + 1] = av.y;
        As[lr][lk + 2] = av.z; As[lr][lk + 3] = av.w;
        Bs[lr][lk + 0] = bv.x; Bs[lr][lk + 1] = bv.y;
        Bs[lr][lk + 2] = bv.z; Bs[lr][lk + 3] = bv.w;
        __syncthreads();
#pragma unroll 4
        for (int kk = 0; kk < 16; ++kk) {
            double a[4], b[4];
#pragma unroll
            for (int i = 0; i < 4; ++i) a[i] = (double)As[4 * ty + i][kk];
#pragma unroll
            for (int j = 0; j < 4; ++j) b[j] = (double)Bs[4 * tx + j][kk];
#pragma unroll
            for (int i = 0; i < 4; ++i)
#pragma unroll
                for (int j = 0; j < 4; ++j) acc[i][j] = fma(a[i], b[j], acc[i][j]);
        }
    }
#pragma unroll
    for (int i = 0; i < 4; ++i)
#pragma unroll
        for (int j = 0; j < 4; ++j)
            Out[(size_t)(row0 + 4 * ty + i) * ldo + col0 + 4 * tx + j] = (float)acc[i][j];
}

// ---- Symmetric Gram GEMM: G = C*C^T (upper blocks + mirror) + Gdiag on diag blocks ----
__global__ __launch_bounds__(256) void k_gemm_sym(
        const float* __restrict__ C, float* __restrict__ Out,
        float* __restrict__ Gdiag) {
    __shared__ float As[64][17];
    __shared__ float Bs[64][17];
    __shared__ float Tr[64][65];
    int tid = threadIdx.x;
    int ty = tid >> 4, tx = tid & 15;
    int t = blockIdx.x, bi = 0;
    while (t >= 32 - bi) { t -= 32 - bi; ++bi; }
    int bj = bi + t;
    int row0 = bi * 64, col0 = bj * 64;
    int lr = tid >> 2, lk = (tid & 3) * 4;
    double acc[4][4] = {};
    for (int k0 = 0; k0 < DIMD; k0 += 16) {
        float4 av = *(const float4*)(C + (size_t)(row0 + lr) * DIMD + k0 + lk);
        float4 bv = *(const float4*)(C + (size_t)(col0 + lr) * DIMD + k0 + lk);
        __syncthreads();
        As[lr][lk + 0] = av.x; As[lr][lk + 1] = av.y;
        As[lr][lk + 2] = av.z; As[lr][lk + 3] = av.w;
        Bs[lr][lk + 0] = bv.x; Bs[lr][lk + 1] = bv.y;
        Bs[lr][lk + 2] = bv.z; Bs[lr][lk + 3] = bv.w;
        __syncthreads();
#pragma unroll 4
        for (int kk = 0; kk < 16; ++kk) {
            double a[4], b[4];
#pragma unroll
            for (int i = 0; i < 4; ++i) a[i] = (double)As[4 * ty + i][kk];
#pragma unroll
            for (int j = 0; j < 4; ++j) b[j] = (double)Bs[4 * tx + j][kk];
#pragma unroll
            for (int i = 0; i < 4; ++i)
#pragma unroll
                for (int j = 0; j < 4; ++j) acc[i][j] = fma(a[i], b[j], acc[i][j]);
        }
    }
#pragma unroll
    for (int i = 0; i < 4; ++i)
#pragma unroll
        for (int j = 0; j < 4; ++j) {
            Out[(size_t)(row0 + 4 * ty + i) * W2 + col0 + 4 * tx + j] = (float)acc[i][j];
            if (bi == bj && (4 * ty + i) == (4 * tx + j))
                Gdiag[row0 + 4 * ty + i] = (float)acc[i][j];
        }
    if (bi != bj) {
        __syncthreads();
#pragma unroll
        for (int i = 0; i < 4; ++i)
#pragma unroll
            for (int j = 0; j < 4; ++j)
                Tr[4 * tx + j][4 * ty + i] = (float)acc[i][j];
        __syncthreads();
#pragma unroll
        for (int i = 0; i < 4; ++i)
#pragma unroll
            for (int j = 0; j < 4; ++j)
                Out[(size_t)(col0 + 4 * ty + i) * W2 + row0 + 4 * tx + j] = Tr[4 * ty + i][4 * tx + j];
    }
}

// ---- persistent fused kernel, 512 threads = 2 sort-teams per batch row ----
__global__ __launch_bounds__(512) void k_iter5(
        const float* __restrict__ G, const float* __restrict__ Xc,
        const float* __restrict__ Gdiag, const float* __restrict__ Xw,
        const float* __restrict__ bias, const float* __restrict__ x,
        int* __restrict__ out) {
    int b = blockIdx.x, tid = threadIdx.x;
    int team = tid >> 8, ttid = tid & 255;
    int lane = tid & 63;
    __shared__ float Dsh[28 * 256];          // 28 KB
    __shared__ float Ecr[NCBK * NCBK * 16];  // 4 KB (1024 entries)
    __shared__ int idxL[NCBK];
    __shared__ int jm[NCBK];
    __shared__ double gmat[64], Xcj[NCBK], Sj[NCBK], jdiag[NCBK];
    __shared__ double xes_sh, xnb_sh;
    __shared__ int changed_sh;
    __shared__ double tv[NCBK][16];
    __shared__ int tk[NCBK][16];
    __shared__ int amr[NCBK][16];
    __shared__ double l1v[4][16]; __shared__ int l1k[4][16];
    __shared__ double l2v[2][16]; __shared__ int l2k[2][16];
    __shared__ double cv[2][64]; __shared__ int ck[2][64];
    __shared__ double tmpV[2][16]; __shared__ int tmpK[2][16];

    // ---- prologue: xnorm (uniform-shift invariant) ----
    {
        float xv = (tid < DIMD) ? x[(size_t)b * DIMD + tid] : 0.f;
        double s = (double)xv * xv;
#pragma unroll
        for (int st = 32; st > 0; st >>= 1) s += __shfl_down(s, st, 64);
        if (lane == 0 && tid < DIMD) cv[0][tid >> 6] = s;
    }
    __syncthreads();
    if (tid == 0) xnb_sh = cv[0][0] + cv[0][1] + cv[0][2] + cv[0][3];
    __syncthreads();
    double xnb = xnb_sh;

    // iteration-invariant per-thread values: team covers codebooks 4*team..4*team+3
    float xcr[4], gdr[4];
#pragma unroll
    for (int i = 0; i < 4; ++i) {
        int n = 4 * team + i;
        xcr[i] = Xc[(size_t)b * W2 + n * CBN + ttid];
        gdr[i] = Gdiag[n * CBN + ttid];
    }

    // ---- initial argmax: first max of (Xw+bias) == argmin of (-val, idx) ----
#pragma unroll
    for (int i = 0; i < 4; ++i) {
        int n = 4 * team + i;
        double v = -((double)Xw[(size_t)b * W2 + n * CBN + ttid] + (double)bias[n * CBN + ttid]);
        argmin_256t(v, ttid, ttid, cv[team], ck[team], tmpV[team], tmpK[team]);
        if (ttid == 0) idxL[n] = tmpK[team][0];
    }
    __syncthreads();

    for (int it = 0; it < NITR; ++it) {
        if (tid < NCBK) jm[tid] = tid * CBN + idxL[tid];
        __syncthreads();

        if (tid < 64) gmat[tid] = (double)G[(size_t)jm[tid >> 3] * W2 + jm[tid & 7]];
        if (tid >= 64 && tid < 72) Xcj[tid - 64] = (double)Xc[(size_t)b * W2 + jm[tid - 64]];
        if (tid >= 72 && tid < 80) jdiag[tid - 72] = (double)Gdiag[jm[tid - 72]];
        __syncthreads();
        if (tid < NCBK) {
            double s = 0.0;
            for (int mp = 0; mp < NCBK; ++mp) s += gmat[mp * 8 + tid];
            Sj[tid] = s - Xcj[tid];
        }
        __syncthreads();
        if (tid == 0) {
            double e = xnb;
            for (int m = 0; m < NCBK; ++m) e += Sj[m] - Xcj[m];
            xes_sh = e;
        }
        __syncthreads();

        // ---- cost phase: team handles 4 codebooks, pipelined 8-row prefetch ----
        {
            int jr[NCBK];
#pragma unroll
            for (int m = 0; m < NCBK; ++m) jr[m] = jm[m];
            int n0 = 4 * team;
            float cur[NCBK], nxt[NCBK];
#pragma unroll
            for (int m = 0; m < NCBK; ++m) cur[m] = G[(size_t)jr[m] * W2 + n0 * CBN + ttid];
#pragma unroll
            for (int i = 0; i < 4; ++i) {
                int n = n0 + i;
                if (i < 3) {
#pragma unroll
                    for (int m = 0; m < NCBK; ++m)
                        nxt[m] = G[(size_t)jr[m] * W2 + (n + 1) * CBN + ttid];
                }
                double s = -(double)xcr[i];
                double gjn = 0.0;
#pragma unroll
                for (int m = 0; m < NCBK; ++m) {
                    double g = (double)cur[m];
                    s += g;
                    if (m == n) gjn = g;
                }
                double cost = (xes_sh - 2.0 * Sj[n] + jdiag[n]) + 2.0 * (s - gjn) + (double)gdr[i];
                top16_256t(cost, ttid, ttid, cv[team], ck[team], &tv[n][0], &tk[n][0]);
                if (i < 3) {
#pragma unroll
                    for (int m = 0; m < NCBK; ++m) cur[m] = nxt[m];
                }
            }
        }
        if (tid < 128) { int m = tid >> 4, i = tid & 15; amr[m][i] = m * CBN + tk[m][i]; }
        __syncthreads();

        // ---- Ecr via G symmetry: 1024 entries / 512 threads = 2 each (FIXED) ----
#pragma unroll
        for (int e = 0; e < 2; ++e) {
            int t = tid + e * 512;
            int m = t >> 7, nn = (t >> 4) & 7, ii = t & 15;
            Ecr[t] = G[(size_t)jm[nn] * W2 + amr[m][ii]];
        }
        __syncthreads();

        // ---- D-tiles: 7168 entries / 512 threads = 14 gathers each ----
        {
            float dreg[14];
#pragma unroll
            for (int e = 0; e < 14; ++e) {
                int t = tid + e * 512;
                int p = t >> 8, ij = t & 255, i = ij >> 4, j = ij & 15;
                dreg[e] = G[(size_t)amr[PM28[p]][i] * W2 + amr[PN28[p]][j]];
            }
#pragma unroll
            for (int e = 0; e < 14; ++e) {
                int t = tid + e * 512;
                int p = t >> 8, ij = t & 255, i = ij >> 4, j = ij & 15;
                int m = PM28[p], n = PN28[p];
                double v = (double)dreg[e]
                         - (double)Ecr[m * 128 + n * 16 + i]
                         - (double)Ecr[n * 128 + m * 16 + j]
                         + gmat[m * 8 + n];
                Dsh[t] = (float)v;
            }
        }
        __syncthreads();
        double xes = xes_sh;

        // ---- tournament level 1: 4 merges in 2 team-parallel rounds ----
        for (int r = 0; r < 2; ++r) {
            int g = 2 * r + team;
            int i = ttid >> 4, j = ttid & 15;
            double val = tv[2 * g][i] + tv[2 * g + 1][j] - xes
                       + 2.0 * (double)Dsh[pidx(2 * g, 2 * g + 1) * 256 + ttid];
            top16_256t(val, ttid, ttid, cv[team], ck[team], &l1v[g][0], &l1k[g][0]);
        }
        // ---- level 2: 2 merges, 1 team-parallel round ----
        {
            int G2 = team;
            int a = ttid >> 4, b2 = ttid & 15;
            int pe = l1k[2 * G2][a], po = l1k[2 * G2 + 1][b2];
            int ie = pe >> 4, io = pe & 15, je = po >> 4, jo = po & 15;
            int c0 = 4 * G2, c1 = 4 * G2 + 1, c2 = 4 * G2 + 2, c3 = 4 * G2 + 3;
            double cross = (double)Dsh[pidx(c0, c2) * 256 + ie * 16 + je]
                         + (double)Dsh[pidx(c0, c3) * 256 + ie * 16 + jo]
                         + (double)Dsh[pidx(c1, c2) * 256 + io * 16 + je]
                         + (double)Dsh[pidx(c1, c3) * 256 + io * 16 + jo];
            double val = l1v[2 * G2][a] + l1v[2 * G2 + 1][b2] - xes + 2.0 * cross;
            top16_256t(val, ttid, ttid, cv[team], ck[team], &tmpV[team][0], &tmpK[team][0]);
            if (ttid < 16) {
                l2v[G2][ttid] = tmpV[team][ttid];
                int kk = tmpK[team][ttid];
                l2k[G2][ttid] = (l1k[2 * G2][kk >> 4] << 8) | l1k[2 * G2 + 1][kk & 15];
            }
            __syncthreads();
        }
        // ---- level 3: final merge + stable argmin (teams duplicate; harmless) ----
        {
            int a = ttid >> 4, b2 = ttid & 15;
            int p0 = l2k[0][a], p1 = l2k[1][b2];
            int se[4] = { (p0 >> 12) & 15, (p0 >> 8) & 15, (p0 >> 4) & 15, p0 & 15 };
            int so[4] = { (p1 >> 12) & 15, (p1 >> 8) & 15, (p1 >> 4) & 15, p1 & 15 };
            double cross = 0.0;
#pragma unroll
            for (int mm = 0; mm < 4; ++mm)
#pragma unroll
                for (int q = 0; q < 4; ++q)
                    cross += (double)Dsh[pidx(mm, 4 + q) * 256 + se[mm] * 16 + so[q]];
            double val = l2v[0][a] + l2v[1][b2] - xes + 2.0 * cross;
            argmin_512(val, ttid, tid, &cv[0][0], &ck[0][0], &tmpV[0][0], &tmpK[0][0]);
            if (tid == 0) {
                int k = tmpK[0][0];
                int a0 = k >> 4, b0 = k & 15;
                int p0w = l2k[0][a0], p1w = l2k[1][b0];
                int sl[8] = { (p0w >> 12) & 15, (p0w >> 8) & 15, (p0w >> 4) & 15, p0w & 15,
                              (p1w >> 12) & 15, (p1w >> 8) & 15, (p1w >> 4) & 15, p1w & 15 };
                int changed = 0;
                for (int n = 0; n < NCBK; ++n) {
                    int ci = tk[n][sl[n]];
                    if (ci != idxL[n]) changed = 1;
                    idxL[n] = ci;
                }
                changed_sh = changed;
            }
        }
        __syncthreads();
        if (!changed_sh) break;
    }
    if (tid < NCBK) out[b * NCBK + tid] = idxL[tid];
}

extern "C" void kernel_launch(void* const* d_in, const int* in_sizes, int n_in,
                              void* d_out, int out_size, void* d_ws, size_t ws_size,
                              hipStream_t stream) {
    const float* x    = (const float*)d_in[0];  // (512, 256)
    const float* w    = (const float*)d_in[1];  // (2048, 256)
    const float* bias = (const float*)d_in[2];  // (2048,)
    const float* c    = (const float*)d_in[3];  // (2048, 256)
    int* out = (int*)d_out;                     // (512, 8) int32
    char* ws = (char*)d_ws;

    // workspace layout (~25.2 MB, fp32 tables)
    float*  G     = (float*) (ws);               // 2048*2048*4 = 16,777,216
    float*  Xc    = (float*) (ws + 16777216);    // 512*2048*4 = 4,194,304
    float*  Xw    = (float*) (ws + 20971520);    // 512*2048*4 = 4,194,304
    float*  Gdiag = (float*) (ws + 25165824);    // 2048*4     = 8,192

    k_gemm_nt<<<dim3(32, 8), 256, 0, stream>>>(x, w, Xw, W2);
    k_gemm_nt<<<dim3(32, 8), 256, 0, stream>>>(x, c, Xc, W2);
    k_gemm_sym<<<528, 256, 0, stream>>>(c, G, Gdiag);
    k_iter5<<<NB, 512, 0, stream>>>(G, Xc, Gdiag, Xw, bias, x, out);
}